// Round 10
// baseline (314.031 us; speedup 1.0000x reference)
//
#include <hip/hip_runtime.h>
#include <math.h>

#define B_ 4
#define C_ 128
#define N_ 4096
#define NSPLIT 4
#define MT 32     // keys per iteration
#define PLD 40    // Ps row stride (shorts): 32 + 8 pad (80 B, 16B-divisible)
#define HLD 136   // h/q/k tile row stride (shorts): 128 + 8 pad
#define VTLD 40   // v-tile row stride (shorts): 32 + 8 pad
#define NBLK 512u

typedef float floatx4 __attribute__((ext_vector_type(4)));
typedef short bf16x8 __attribute__((ext_vector_type(8)));

__device__ __forceinline__ ushort f2bf(float f) {  // RNE
  unsigned u = __float_as_uint(f);
  return (ushort)((u + 0x7FFF + ((u >> 16) & 1)) >> 16);
}
__device__ __forceinline__ float bf2f(ushort u) {
  return __uint_as_float(((unsigned)u) << 16);
}
__device__ __forceinline__ unsigned pkbf(float a, float b) {
  return __builtin_amdgcn_perm(__float_as_uint(a) + 0x8000u,
                               __float_as_uint(b) + 0x8000u, 0x07060302u);
}
__device__ __forceinline__ float fexp2(float x) {
#if __has_builtin(__builtin_amdgcn_exp2f)
  return __builtin_amdgcn_exp2f(x);
#else
  return exp2f(x);
#endif
}
__device__ __forceinline__ void gl2lds16(const ushort* g, ushort* l) {
  __builtin_amdgcn_global_load_lds(
      (const __attribute__((address_space(1))) void*)g,
      (__attribute__((address_space(3))) void*)l, 16, 0, 0);
}

// Flag/poller grid barrier, monotonic generations (phase = 1,2,3).
// R9's hierarchical counter still cost ~46us/barrier: arrivals were agent-scope
// RMWs SERIALIZED on shared cachelines (~0.7us each x 64/leaf).  Fix: arrivals are
// independent release-STORES to per-block flag slots (parallel, no RMW serialization).
// Block 0's 512 threads acquire-poll all 512 flags concurrently, syncthreads, then
// tid0 release-stores the generation; all other blocks acquire-poll the generation.
// HB chain: writes -> flag store(rel, L2 wb) -> blk0 flag load(acq) -> syncthreads
// -> gen store(rel) -> gen load(acq) -> reads.  Same fence semantics as R8/R9 (passed).
// Layout (uint idx): bar[0]=gen; bar[64 + bx*4]=flag for block bx (16B stride).
__device__ __forceinline__ void grid_bar(unsigned* bar, unsigned phase) {
  __syncthreads();
  unsigned* flags = bar + 64;
  if (blockIdx.x == 0) {
    if (threadIdx.x == 0)
      __hip_atomic_store(&flags[0], phase, __ATOMIC_RELEASE, __HIP_MEMORY_SCOPE_AGENT);
    unsigned t = threadIdx.x;   // 512 threads poll 512 flags in parallel
    while (__hip_atomic_load(&flags[t * 4], __ATOMIC_ACQUIRE, __HIP_MEMORY_SCOPE_AGENT) < phase)
      __builtin_amdgcn_s_sleep(2);
    __syncthreads();
    if (threadIdx.x == 0)
      __hip_atomic_store(&bar[0], phase, __ATOMIC_RELEASE, __HIP_MEMORY_SCOPE_AGENT);
    __syncthreads();
  } else {
    if (threadIdx.x == 0) {
      __hip_atomic_store(&flags[blockIdx.x * 4], phase, __ATOMIC_RELEASE, __HIP_MEMORY_SCOPE_AGENT);
      while (__hip_atomic_load(&bar[0], __ATOMIC_ACQUIRE, __HIP_MEMORY_SCOPE_AGENT) < phase)
        __builtin_amdgcn_s_sleep(16);
    }
    __syncthreads();
  }
}

// =====================================================================================
// ONE kernel, 4 phases separated by flag/poller grid barriers.
// grid 512 x 512 thr, 54,272 B LDS (attn footprint; overlaid per phase),
// launch_bounds(512,4) -> exactly 2 blocks/CU x 256 CU co-resident.
// Phase roles per block (bx = 0..511):
//   P0: bx<256 -> gn-stats task (b,g,part); bx>=256 -> weight bf16 convert.
//   P1: gnqkv, (b, 32-n tile) = (bx>>7, bx&127).  8 waves x 16 out-ch.
//   P2: attn (R3/R6-identical structure), sp=bx&3, qblk=(bx>>2)&31, b=bx>>7.
//   P3: mergeproj, (b, 32-n tile).  8 waves x 16 out-ch.
// =====================================================================================
__global__ __launch_bounds__(512, 4) void fused_kernel(
    const float* __restrict__ x, const float* __restrict__ gn_scale,
    const float* __restrict__ gn_bias,
    const float* __restrict__ wq, const float* __restrict__ bq,
    const float* __restrict__ wk, const float* __restrict__ bk,
    const float* __restrict__ wv, const float* __restrict__ bv,
    const float* __restrict__ wp, const float* __restrict__ bp,
    float* __restrict__ out, unsigned* __restrict__ bar,
    float* __restrict__ Lv, ushort* __restrict__ wB,
    float* __restrict__ gstat, ushort* __restrict__ qT, ushort* __restrict__ kT,
    ushort* __restrict__ vB, ushort* __restrict__ Op) {
  __shared__ __align__(16) char smem[54272];
  ushort* sm_u = (ushort*)smem;
  int bx = blockIdx.x;
  int tid = threadIdx.x, lane = tid & 63, w = tid >> 6;
  int col = lane & 15, quad = lane >> 4;

  // ---------------- P0: gn stats + weight convert ----------------
  if (bx >= 256) {   // weight convert: 65536 elems over 256 blocks
    if (tid < 256) {
      int i = (bx - 256) * 256 + tid;
      int m = i >> 14, j = i & 16383;
      const float* src = (m == 0) ? wq : (m == 1) ? wk : (m == 2) ? wv : wp;
      wB[i] = f2bf(src[j]);
    }
  } else {
    int b = bx >> 6, g = (bx >> 3) & 7, part = bx & 7;
    const float4* xp = (const float4*)(x + (size_t)(b * C_ + g * 16) * N_) + part * 2048;
    float s = 0.f, ss = 0.f;
    for (int i = tid; i < 2048; i += 512) {
      float4 v = xp[i];
      s += v.x + v.y + v.z + v.w;
      ss += v.x * v.x + v.y * v.y + v.z * v.z + v.w * v.w;
    }
    #pragma unroll
    for (int o = 32; o > 0; o >>= 1) {
      s += __shfl_down(s, o, 64);
      ss += __shfl_down(ss, o, 64);
    }
    float* rs = (float*)smem;        // 8 floats
    float* rss = (float*)smem + 8;   // 8 floats
    if (lane == 0) { rs[w] = s; rss[w] = ss; }
    __syncthreads();
    if (tid == 0) {
      float S = 0.f, SS = 0.f;
      #pragma unroll
      for (int k = 0; k < 8; ++k) { S += rs[k]; SS += rss[k]; }
      int slot = (b * 8 + g) * 8 + part;
      gstat[slot]       = S;
      gstat[256 + slot] = SS;
    }
  }
  grid_bar(bar, 1u);

  // ---------------- P1: GN-apply + QKV MFMA ----------------
  {
    ushort* hs = sm_u;               // [32][HLD]   8704 B
    ushort* Qt = sm_u + 4352;        // [32][HLD]
    ushort* Kt = sm_u + 8704;        // [32][HLD]
    ushort* Vt = sm_u + 13056;       // [128][VTLD] 10240 B
    float* sSc = (float*)(smem + 36352);
    float* sBi = (float*)(smem + 36864);
    int b = bx >> 7;
    int n0 = (bx & 127) * 32;
    if (tid < 128) {
      int g = tid >> 4;
      float S = 0.f, SS = 0.f;
      #pragma unroll
      for (int p = 0; p < 8; ++p) {
        S  += gstat[(b * 8 + g) * 8 + p];
        SS += gstat[256 + (b * 8 + g) * 8 + p];
      }
      float mu = S * (1.f / 65536.f);
      float var = SS * (1.f / 65536.f) - mu * mu;
      float rstd = rsqrtf(var + 1e-6f);
      float sc = gn_scale[tid] * rstd;
      sSc[tid] = sc;
      sBi[tid] = gn_bias[tid] - mu * sc;
    }
    __syncthreads();
    #pragma unroll
    for (int k2 = 0; k2 < 2; ++k2) {   // 128 c x 8 float4 (32 n) = 1024
      int i = tid + k2 * 512;
      int c = i >> 3, n4 = i & 7;
      float4 v = *(const float4*)(x + (size_t)(b * C_ + c) * N_ + n0 + n4 * 4);
      float sc = sSc[c], bi = sBi[c];
      hs[(n4 * 4 + 0) * HLD + c] = f2bf(v.x * sc + bi);
      hs[(n4 * 4 + 1) * HLD + c] = f2bf(v.y * sc + bi);
      hs[(n4 * 4 + 2) * HLD + c] = f2bf(v.z * sc + bi);
      hs[(n4 * 4 + 3) * HLD + c] = f2bf(v.w * sc + bi);
    }
    __syncthreads();
    int o0 = w * 16;   // 8 waves x 16 output channels
    bf16x8 hf[2][4];   // [n-half][kc]
    #pragma unroll
    for (int nh = 0; nh < 2; ++nh)
      #pragma unroll
      for (int kc = 0; kc < 4; ++kc)
        hf[nh][kc] = *(const bf16x8*)&hs[(nh * 16 + col) * HLD + kc * 32 + quad * 8];
    const ushort* Wq = wB;
    const ushort* Wk = wB + 16384;
    const ushort* Wv = wB + 32768;
    const float scl = 0.12751879752224991f;  // 128^-0.5 * log2(e)
    floatx4 aq[2] = {(floatx4)0.f, (floatx4)0.f};
    floatx4 ak[2] = {(floatx4)0.f, (floatx4)0.f};
    floatx4 av[2] = {(floatx4)0.f, (floatx4)0.f};
    #pragma unroll
    for (int kc = 0; kc < 4; ++kc) {
      int wo = (o0 + col) * C_ + kc * 32 + quad * 8;
      bf16x8 wqf = *(const bf16x8*)&Wq[wo];
      bf16x8 wkf = *(const bf16x8*)&Wk[wo];
      bf16x8 wvf = *(const bf16x8*)&Wv[wo];
      #pragma unroll
      for (int nh = 0; nh < 2; ++nh) {
        aq[nh] = __builtin_amdgcn_mfma_f32_16x16x32_bf16(wqf, hf[nh][kc], aq[nh], 0, 0, 0);
        ak[nh] = __builtin_amdgcn_mfma_f32_16x16x32_bf16(wkf, hf[nh][kc], ak[nh], 0, 0, 0);
        av[nh] = __builtin_amdgcn_mfma_f32_16x16x32_bf16(wvf, hf[nh][kc], av[nh], 0, 0, 0);
      }
    }
    float4 bqv = *(const float4*)&bq[o0 + quad * 4];
    float4 bkv = *(const float4*)&bk[o0 + quad * 4];
    float4 bvv = *(const float4*)&bv[o0 + quad * 4];
    #pragma unroll
    for (int nh = 0; nh < 2; ++nh) {
      uint2 qs = { pkbf((aq[nh][1] + bqv.y) * scl, (aq[nh][0] + bqv.x) * scl),
                   pkbf((aq[nh][3] + bqv.w) * scl, (aq[nh][2] + bqv.z) * scl) };
      uint2 ks = { pkbf(ak[nh][1] + bkv.y, ak[nh][0] + bkv.x),
                   pkbf(ak[nh][3] + bkv.w, ak[nh][2] + bkv.z) };
      *(uint2*)&Qt[(nh * 16 + col) * HLD + o0 + quad * 4] = qs;
      *(uint2*)&Kt[(nh * 16 + col) * HLD + o0 + quad * 4] = ks;
      float vv[4] = {av[nh][0] + bvv.x, av[nh][1] + bvv.y,
                     av[nh][2] + bvv.z, av[nh][3] + bvv.w};
      #pragma unroll
      for (int r = 0; r < 4; ++r)
        Vt[(o0 + quad * 4 + r) * VTLD + nh * 16 + col] = f2bf(vv[r]);
    }
    __syncthreads();
    {
      int row = tid >> 4, seg = tid & 15;   // 32 rows x 16 segs
      size_t dst = ((size_t)b * N_ + n0 + row) * C_ + seg * 8;
      *(uint4*)(qT + dst) = *(const uint4*)&Qt[row * HLD + seg * 8];
      *(uint4*)(kT + dst) = *(const uint4*)&Kt[row * HLD + seg * 8];
    }
    {
      int o = tid >> 2, seg = tid & 3;      // 128 ch x 4 segs
      *(uint4*)(vB + ((size_t)b * C_ + o) * N_ + n0 + seg * 8) =
          *(const uint4*)&Vt[o * VTLD + seg * 8];
    }
  }
  grid_bar(bar, 2u);

  // ---------------- P2: flash attention (R3/R6 structure, flat LDS) ----------------
  {
    ushort* Ks = sm_u;            // [2][4096] shorts (chunk-swizzled by row&7)
    ushort* Vs = sm_u + 8192;     // [2][4096] shorts (chunk-swizzled by (c>>1)&3)
    ushort* Ps = sm_u + 16384;    // [2][5120] shorts, double-buffered
    float* lpart = (float*)(smem + 53248);  // [8][2][16]
    int sp = bx & 3;
    int qblk = (bx >> 2) & 31;
    int b = bx >> 7;
    int n0 = qblk * 128;
    int wu = __builtin_amdgcn_readfirstlane(w);
    int mtw = w & 1, qg = w >> 1;   // S-phase roles
    int qh = w & 1, cq = w >> 1;    // PV-phase roles
    const ushort* kTb = kT + (size_t)b * N_ * C_;
    const ushort* vBb = vB + (size_t)b * C_ * N_;

    bf16x8 qf[2][4];
    #pragma unroll
    for (int qt = 0; qt < 2; ++qt)
      #pragma unroll
      for (int kc = 0; kc < 4; ++kc)
        qf[qt][kc] = *(const bf16x8*)(qT + ((size_t)b * N_ + n0 + qg * 32 + qt * 16 + col) * C_ + kc * 32 + quad * 8);

    floatx4 Oacc[4][2];
    #pragma unroll
    for (int qt = 0; qt < 4; ++qt)
      #pragma unroll
      for (int ct = 0; ct < 2; ++ct) Oacc[qt][ct] = (floatx4)0.f;
    float lacc[2] = {0.f, 0.f};

    const int m00 = sp * 1024;
    const ushort* kgp;
    const ushort* vgp;
    {
      int r = wu * 4 + (lane >> 4);
      int pos = (lane & 15) ^ (r & 7);
      kgp = kTb + (size_t)(m00 + r) * 128 + pos * 8;
      int c = wu * 16 + (lane >> 2);
      int mc = (lane & 3) ^ ((lane >> 3) & 3);
      vgp = vBb + (size_t)c * N_ + m00 + mc * 8;
    }

    #define STAGE(buf)                                        \
      {                                                       \
        gl2lds16(kgp, Ks + (buf)*4096 + wu * 512);            \
        gl2lds16(vgp, Vs + (buf)*4096 + wu * 512);            \
        kgp += MT * 128;                                      \
        vgp += MT;                                            \
      }

    #define S_COMPUTE(KsB, st)                                                          \
      {                                                                                 \
        int row = mtw * 16 + col;                                                       \
        bf16x8 kf[4];                                                                   \
        _Pragma("unroll")                                                               \
        for (int kc = 0; kc < 4; ++kc)                                                  \
          kf[kc] = *(const bf16x8*)&(KsB)[row * 128 + (((4 * kc + quad) ^ (col & 7)) * 8)]; \
        __builtin_amdgcn_s_setprio(1);                                                  \
        _Pragma("unroll")                                                               \
        for (int qt = 0; qt < 2; ++qt) {                                                \
          floatx4 acc = (floatx4)0.f;                                                   \
          _Pragma("unroll")                                                             \
          for (int kc = 0; kc < 4; ++kc)                                                \
            acc = __builtin_amdgcn_mfma_f32_16x16x32_bf16(kf[kc], qf[qt][kc], acc, 0, 0, 0); \
          st[qt] = acc;                                                                 \
        }                                                                               \
        __builtin_amdgcn_s_setprio(0);                                                  \
      }

    #define SOFTMAX_WRITE(PsB, st)                                                      \
      {                                                                                 \
        _Pragma("unroll")                                                               \
        for (int qt = 0; qt < 2; ++qt) {                                                \
          int prow = (qg * 32 + qt * 16 + col) * PLD + mtw * 16;                        \
          float p0 = fexp2(st[qt][0]);                                                  \
          float p1 = fexp2(st[qt][1]);                                                  \
          float p2 = fexp2(st[qt][2]);                                                  \
          float p3 = fexp2(st[qt][3]);                                                  \
          uint2 pk = { pkbf(p1, p0), pkbf(p3, p2) };                                    \
          *(uint2*)&(PsB)[prow + quad * 4] = pk;                                        \
          lacc[qt] += (p0 + p1) + (p2 + p3);                                            \
        }                                                                               \
      }

    #define V_LOAD(VsB, vfp)                                                            \
      {                                                                                 \
        _Pragma("unroll")                                                               \
        for (int ct = 0; ct < 2; ++ct)                                                  \
          vfp[ct] = *(const bf16x8*)&(VsB)[(cq * 32 + ct * 16 + col) * MT +             \
                                           ((quad ^ ((col >> 1) & 3)) * 8)];            \
      }

    #define PV_COMPUTE(PsB, vfp)                                                        \
      {                                                                                 \
        __builtin_amdgcn_s_setprio(1);                                                  \
        _Pragma("unroll")                                                               \
        for (int qt = 0; qt < 4; ++qt) {                                                \
          bf16x8 pf = *(const bf16x8*)&(PsB)[(qh * 64 + qt * 16 + col) * PLD + quad * 8]; \
          _Pragma("unroll")                                                             \
          for (int ct = 0; ct < 2; ++ct)                                                \
            Oacc[qt][ct] = __builtin_amdgcn_mfma_f32_16x16x32_bf16(pf, vfp[ct], Oacc[qt][ct], 0, 0, 0); \
        }                                                                               \
        __builtin_amdgcn_s_setprio(0);                                                  \
      }

    floatx4 st[2];
    bf16x8 vfp[2];

    STAGE(0);
    __syncthreads();

    // t = 0 (no PV yet)
    STAGE(1);
    S_COMPUTE(Ks, st);
    SOFTMAX_WRITE(Ps, st);
    V_LOAD(Vs, vfp);
    __syncthreads();

    // steady state t = 1..30: S(t) ; PV(t-1) ; softmax(t) ; vload(t) ; barrier
    for (int t = 1; t < 31; ++t) {
      STAGE((t + 1) & 1);
      S_COMPUTE(Ks + (t & 1) * 4096, st);
      PV_COMPUTE(Ps + ((t - 1) & 1) * 5120, vfp);
      SOFTMAX_WRITE(Ps + (t & 1) * 5120, st);
      V_LOAD(Vs + (t & 1) * 4096, vfp);
      __syncthreads();
    }

    // t = 31 (no stage)
    S_COMPUTE(Ks + 4096, st);
    PV_COMPUTE(Ps, vfp);
    SOFTMAX_WRITE(Ps + 5120, st);
    V_LOAD(Vs + 4096, vfp);
    __syncthreads();

    // drain PV(31)
    PV_COMPUTE(Ps + 5120, vfp);

    // epilogue: Op[sp][b][n][c] bf16 (unnormalized)
    ushort* OpB = Op + (((size_t)sp * B_ + b) * N_ + n0) * C_;
    #pragma unroll
    for (int qt = 0; qt < 4; ++qt)
      #pragma unroll
      for (int ct = 0; ct < 2; ++ct)
        #pragma unroll
        for (int r = 0; r < 4; ++r)
          OpB[(size_t)(qh * 64 + qt * 16 + quad * 4 + r) * C_ + cq * 32 + ct * 16 + col] =
              f2bf(Oacc[qt][ct][r]);
    #pragma unroll
    for (int qt = 0; qt < 2; ++qt) {
      float lsum = lacc[qt];
      lsum += __shfl_xor(lsum, 16, 64);
      lsum += __shfl_xor(lsum, 32, 64);
      if (quad == 0) lpart[(w * 2 + qt) * 16 + col] = lsum;
    }
    __syncthreads();
    if ((w & 1) == 0 && quad == 0) {
      #pragma unroll
      for (int qt = 0; qt < 2; ++qt) {
        int idx = b * N_ + n0 + (w >> 1) * 32 + qt * 16 + col;
        Lv[(size_t)sp * (B_ * N_) + idx] =
            lpart[(w * 2 + qt) * 16 + col] + lpart[((w + 1) * 2 + qt) * 16 + col];
      }
    }
  }
  grid_bar(bar, 3u);

  // ---------------- P3: merge(4 splits) + proj MFMA + residual ----------------
  {
    ushort* tile = sm_u;   // [32][HLD]
    const ushort* wpB = wB + 49152;
    int b = bx >> 7;
    int n0 = (bx & 127) * 32;
    {
      int n = tid >> 4, cc = tid & 15;   // 32 n x 16 cc
      int nIdx = b * N_ + n0 + n;
      float den = Lv[0 * (B_ * N_) + nIdx] + Lv[1 * (B_ * N_) + nIdx] +
                  Lv[2 * (B_ * N_) + nIdx] + Lv[3 * (B_ * N_) + nIdx];
      float inv = 1.f / den;
      float o[8];
      #pragma unroll
      for (int j = 0; j < 8; ++j) o[j] = 0.f;
      #pragma unroll
      for (int sp = 0; sp < NSPLIT; ++sp) {
        uint4 d = *(const uint4*)&Op[((size_t)sp * (B_ * N_) + nIdx) * C_ + cc * 8];
        unsigned dd[4] = {d.x, d.y, d.z, d.w};
        #pragma unroll
        for (int j = 0; j < 4; ++j) {
          o[j * 2]     += bf2f((ushort)(dd[j] & 0xFFFF));
          o[j * 2 + 1] += bf2f((ushort)(dd[j] >> 16));
        }
      }
      uint4 res;
      res.x = pkbf(o[1] * inv, o[0] * inv);
      res.y = pkbf(o[3] * inv, o[2] * inv);
      res.z = pkbf(o[5] * inv, o[4] * inv);
      res.w = pkbf(o[7] * inv, o[6] * inv);
      *(uint4*)&tile[n * HLD + cc * 8] = res;
    }
    __syncthreads();
    int o0 = w * 16;   // 8 waves x 16 output channels
    bf16x8 hf[2][4];
    #pragma unroll
    for (int nh = 0; nh < 2; ++nh)
      #pragma unroll
      for (int kc = 0; kc < 4; ++kc)
        hf[nh][kc] = *(const bf16x8*)&tile[(nh * 16 + col) * HLD + kc * 32 + quad * 8];
    floatx4 acc[2] = {(floatx4)0.f, (floatx4)0.f};
    #pragma unroll
    for (int kc = 0; kc < 4; ++kc) {
      int wo = (o0 + col) * C_ + kc * 32 + quad * 8;
      bf16x8 wf = *(const bf16x8*)&wpB[wo];
      #pragma unroll
      for (int nh = 0; nh < 2; ++nh)
        acc[nh] = __builtin_amdgcn_mfma_f32_16x16x32_bf16(wf, hf[nh][kc], acc[nh], 0, 0, 0);
    }
    float4 bpv = *(const float4*)&bp[o0 + quad * 4];
    float bb[4] = {bpv.x, bpv.y, bpv.z, bpv.w};
    #pragma unroll
    for (int nh = 0; nh < 2; ++nh)
      #pragma unroll
      for (int r = 0; r < 4; ++r) {
        size_t idx = ((size_t)b * C_ + o0 + quad * 4 + r) * N_ + n0 + nh * 16 + col;
        out[idx] = acc[nh][r] + bb[r] + x[idx];
      }
  }
}

extern "C" void kernel_launch(void* const* d_in, const int* in_sizes, int n_in,
                              void* d_out, int out_size, void* d_ws, size_t ws_size,
                              hipStream_t stream) {
  const float* x        = (const float*)d_in[0];
  const float* gn_scale = (const float*)d_in[1];
  const float* gn_bias  = (const float*)d_in[2];
  const float* wq = (const float*)d_in[3];
  const float* bq = (const float*)d_in[4];
  const float* wk = (const float*)d_in[5];
  const float* bk = (const float*)d_in[6];
  const float* wv = (const float*)d_in[7];
  const float* bv = (const float*)d_in[8];
  const float* wp = (const float*)d_in[9];
  const float* bp = (const float*)d_in[10];
  float* out = (float*)d_out;

  char* ws = (char*)d_ws;
  unsigned* bar = (unsigned*)ws;                 // barrier state (reset every replay)
  float*  Lv    = (float*)(ws + 262144);
  ushort* wB    = (ushort*)(ws + 524288);
  float*  gstat = (float*)(ws + 655360);
  ushort* qT    = (ushort*)(ws + (4u << 20));
  ushort* kT    = (ushort*)(ws + (8u << 20));
  ushort* vB    = (ushort*)(ws + (12u << 20));
  ushort* Op    = (ushort*)(ws + (16u << 20));

  hipMemsetAsync(bar, 0, 16384, stream);
  fused_kernel<<<512, 512, 0, stream>>>(x, gn_scale, gn_bias, wq, bq, wk, bk,
                                        wv, bv, wp, bp, out, bar, Lv, wB, gstat,
                                        qT, kT, vB, Op);
}

// Round 11
// 142.729 us; speedup vs baseline: 2.2002x; 2.2002x over previous
//
#include <hip/hip_runtime.h>
#include <math.h>

#define B_ 4
#define C_ 128
#define N_ 4096
#define NSPLIT 4
#define MT 32     // keys per iteration
#define PLD 40    // Ps row stride (shorts): 32 + 8 pad (80 B, 16B-divisible)
#define HLD 136   // h/q/k tile row stride (shorts): 128 + 8 pad
#define VTLD 40   // gnqkv v-tile row stride (shorts): 32 + 8 pad (80 B, 16B-divisible)

typedef float floatx4 __attribute__((ext_vector_type(4)));
typedef short bf16x8 __attribute__((ext_vector_type(8)));

__device__ __forceinline__ ushort f2bf(float f) {  // RNE
  unsigned u = __float_as_uint(f);
  return (ushort)((u + 0x7FFF + ((u >> 16) & 1)) >> 16);
}
__device__ __forceinline__ float bf2f(ushort u) {
  return __uint_as_float(((unsigned)u) << 16);
}
// pack two floats -> (hi16(a)<<16)|hi16(b), round-half-up
__device__ __forceinline__ unsigned pkbf(float a, float b) {
  return __builtin_amdgcn_perm(__float_as_uint(a) + 0x8000u,
                               __float_as_uint(b) + 0x8000u, 0x07060302u);
}
// raw v_exp_f32 (exp2) -- OCML exp2f is ~10 inst of denorm/range handling we don't need
__device__ __forceinline__ float fexp2(float x) {
#if __has_builtin(__builtin_amdgcn_exp2f)
  return __builtin_amdgcn_exp2f(x);
#else
  return exp2f(x);
#endif
}
// async global -> LDS, 16B per lane; LDS dest = uniform base + lane*16
__device__ __forceinline__ void gl2lds16(const ushort* g, ushort* l) {
  __builtin_amdgcn_global_load_lds(
      (const __attribute__((address_space(1))) void*)g,
      (__attribute__((address_space(3))) void*)l, 16, 0, 0);
}

// NOTE (R7-R10): single-kernel fusion with grid-wide barriers was tried 4 ways --
// cooperative launch (failed under graph capture), flat atomic counter (77us/bar),
// hierarchical counters (46us/bar), flag+central-gen (60us/bar).  Software grid
// barriers cost >=45us each on MI355X (some segment always serializes at cross-XCD
// coherence latency ~0.5-1us x O(64-512)); the inter-kernel overhead they would
// recover is only ~60us total.  Multi-kernel structure is the right design here.

// ---------------- fused: gn_stats (blocks 0..255) + weight cvt (256..511) ----------------
__global__ __launch_bounds__(256) void prep_kernel(
    const float* __restrict__ x, float* __restrict__ gstat,
    const float* __restrict__ wq, const float* __restrict__ wk,
    const float* __restrict__ wv, const float* __restrict__ wp,
    ushort* __restrict__ wB) {
  if (blockIdx.x >= 256) {   // weight convert: 65536 elems
    int i = (blockIdx.x - 256) * 256 + threadIdx.x;
    int m = i >> 14, j = i & 16383;
    const float* src = (m == 0) ? wq : (m == 1) ? wk : (m == 2) ? wv : wp;
    wB[i] = f2bf(src[j]);
    return;
  }
  int b = blockIdx.x >> 6, g = (blockIdx.x >> 3) & 7, part = blockIdx.x & 7;
  const float4* xp = (const float4*)(x + (size_t)(b * C_ + g * 16) * N_) + part * 2048;
  float s = 0.f, ss = 0.f;
  for (int i = threadIdx.x; i < 2048; i += 256) {
    float4 v = xp[i];
    s += v.x + v.y + v.z + v.w;
    ss += v.x * v.x + v.y * v.y + v.z * v.z + v.w * v.w;
  }
  #pragma unroll
  for (int o = 32; o > 0; o >>= 1) {
    s += __shfl_down(s, o, 64);
    ss += __shfl_down(ss, o, 64);
  }
  __shared__ float rs[4], rss[4];
  int wid = threadIdx.x >> 6, lane = threadIdx.x & 63;
  if (lane == 0) { rs[wid] = s; rss[wid] = ss; }
  __syncthreads();
  if (threadIdx.x == 0) {
    int slot = (b * 8 + g) * 8 + part;
    gstat[slot]       = rs[0] + rs[1] + rs[2] + rs[3];
    gstat[256 + slot] = rss[0] + rss[1] + rss[2] + rss[3];
  }
}

// ---------------- fused GN-apply + QKV MFMA: grid 512 = (b, 32-n tile) ----------------
// Widened 16->32 n per block: weight A-frags loaded once per (ot,kc), reused for both
// n-halves (halves L2 weight traffic); x loads 128B contiguous per channel; per-block
// fixed costs (stats read, barriers, epilogue) amortized over 2x MFMA work.
__global__ __launch_bounds__(256) void gnqkv_kernel(
    const float* __restrict__ x, const float* __restrict__ gstat,
    const float* __restrict__ scale, const float* __restrict__ bias,
    const ushort* __restrict__ wB,
    const float* __restrict__ bq, const float* __restrict__ bk,
    const float* __restrict__ bv,
    ushort* __restrict__ qT, ushort* __restrict__ kT, ushort* __restrict__ vB) {
  __shared__ __align__(16) ushort hs[32][HLD];
  __shared__ __align__(16) ushort Qt[32][HLD];
  __shared__ __align__(16) ushort Kt[32][HLD];
  __shared__ __align__(16) ushort Vt[128][VTLD];
  __shared__ float sSc[C_], sBi[C_];
  int tid = threadIdx.x;
  int b = blockIdx.x >> 7;
  int n0 = (blockIdx.x & 127) * 32;
  if (tid < 128) {
    int g = tid >> 4;
    float S = 0.f, SS = 0.f;
    #pragma unroll
    for (int p = 0; p < 8; ++p) {
      S  += gstat[(b * 8 + g) * 8 + p];
      SS += gstat[256 + (b * 8 + g) * 8 + p];
    }
    float mu = S * (1.f / 65536.f);
    float var = SS * (1.f / 65536.f) - mu * mu;
    float rstd = rsqrtf(var + 1e-6f);
    float sc = scale[tid] * rstd;
    sSc[tid] = sc;
    sBi[tid] = bias[tid] - mu * sc;
  }
  __syncthreads();
  #pragma unroll
  for (int k2 = 0; k2 < 4; ++k2) {   // 128 c x 8 float4 (32 n) = 1024
    int i = tid + k2 * 256;
    int c = i >> 3, n4 = i & 7;
    float4 v = *(const float4*)(x + (size_t)(b * C_ + c) * N_ + n0 + n4 * 4);
    float sc = sSc[c], bi = sBi[c];
    hs[n4 * 4 + 0][c] = f2bf(v.x * sc + bi);
    hs[n4 * 4 + 1][c] = f2bf(v.y * sc + bi);
    hs[n4 * 4 + 2][c] = f2bf(v.z * sc + bi);
    hs[n4 * 4 + 3][c] = f2bf(v.w * sc + bi);
  }
  __syncthreads();
  int lane = tid & 63, w = tid >> 6;
  int col = lane & 15, quad = lane >> 4;
  int oh = w * 32;   // each wave: 32 output channels, 32 n
  bf16x8 hf[2][4];   // [n-half][kc]
  #pragma unroll
  for (int nh = 0; nh < 2; ++nh)
    #pragma unroll
    for (int kc = 0; kc < 4; ++kc)
      hf[nh][kc] = *(const bf16x8*)&hs[nh * 16 + col][kc * 32 + quad * 8];
  const ushort* Wq = wB;
  const ushort* Wk = wB + 16384;
  const ushort* Wv = wB + 32768;
  const float scl = 0.12751879752224991f;  // 128^-0.5 * log2(e)
  #pragma unroll
  for (int ot = 0; ot < 2; ++ot) {
    int o0 = oh + ot * 16;
    floatx4 aq[2] = {(floatx4)0.f, (floatx4)0.f};
    floatx4 ak[2] = {(floatx4)0.f, (floatx4)0.f};
    floatx4 av[2] = {(floatx4)0.f, (floatx4)0.f};
    #pragma unroll
    for (int kc = 0; kc < 4; ++kc) {
      int wo = (o0 + col) * C_ + kc * 32 + quad * 8;
      bf16x8 wqf = *(const bf16x8*)&Wq[wo];
      bf16x8 wkf = *(const bf16x8*)&Wk[wo];
      bf16x8 wvf = *(const bf16x8*)&Wv[wo];
      #pragma unroll
      for (int nh = 0; nh < 2; ++nh) {
        aq[nh] = __builtin_amdgcn_mfma_f32_16x16x32_bf16(wqf, hf[nh][kc], aq[nh], 0, 0, 0);
        ak[nh] = __builtin_amdgcn_mfma_f32_16x16x32_bf16(wkf, hf[nh][kc], ak[nh], 0, 0, 0);
        av[nh] = __builtin_amdgcn_mfma_f32_16x16x32_bf16(wvf, hf[nh][kc], av[nh], 0, 0, 0);
      }
    }
    float4 bqv = *(const float4*)&bq[o0 + quad * 4];
    float4 bkv = *(const float4*)&bk[o0 + quad * 4];
    float4 bvv = *(const float4*)&bv[o0 + quad * 4];
    #pragma unroll
    for (int nh = 0; nh < 2; ++nh) {
      uint2 qs = { pkbf((aq[nh][1] + bqv.y) * scl, (aq[nh][0] + bqv.x) * scl),
                   pkbf((aq[nh][3] + bqv.w) * scl, (aq[nh][2] + bqv.z) * scl) };
      uint2 ks = { pkbf(ak[nh][1] + bkv.y, ak[nh][0] + bkv.x),
                   pkbf(ak[nh][3] + bkv.w, ak[nh][2] + bkv.z) };
      *(uint2*)&Qt[nh * 16 + col][o0 + quad * 4] = qs;
      *(uint2*)&Kt[nh * 16 + col][o0 + quad * 4] = ks;
      float vv[4] = {av[nh][0] + bvv.x, av[nh][1] + bvv.y,
                     av[nh][2] + bvv.z, av[nh][3] + bvv.w};
      #pragma unroll
      for (int r = 0; r < 4; ++r)
        Vt[o0 + quad * 4 + r][nh * 16 + col] = f2bf(vv[r]);
    }
  }
  __syncthreads();
  #pragma unroll
  for (int rep = 0; rep < 2; ++rep) {
    int idx = tid + rep * 256;
    int row = idx >> 4, seg = idx & 15;
    size_t dst = ((size_t)b * N_ + n0 + row) * C_ + seg * 8;
    *(uint4*)(qT + dst) = *(const uint4*)&Qt[row][seg * 8];
    *(uint4*)(kT + dst) = *(const uint4*)&Kt[row][seg * 8];
  }
  #pragma unroll
  for (int rep = 0; rep < 2; ++rep) {
    int idx = tid + rep * 256;
    int o = idx >> 2, seg = idx & 3;
    *(uint4*)(vB + ((size_t)b * C_ + o) * N_ + n0 + seg * 8) = *(const uint4*)&Vt[o][seg * 8];
  }
}

// ---------------- MFMA flash attention: 8-wave blocks, split-m S + split-qc PV ----------
// grid 512: sp=bx&3 (fastest; XCD x sees only sp=x&3 -> K/V slice L2-resident),
// qblk=(bx>>2)&31, b=bx>>7.  512 thr = 8 waves.
// S-phase:  wave w -> m-half mtw=w&1 (16 keys), q-group qg=w>>1 (32 q).
// PV-phase: wave w -> q-half qh=w&1 (64 q), channel-quarter cq=w>>1 (32 c).
// SOFTWARE PIPELINE (1 barrier/iter): Ps double-buffered; PV runs one tile behind.
// exp2 = raw v_exp_f32. STAGE pointers hoisted. K chunk-swizzled by row&7; Vs m-chunk
// swizzled by (c>>1)&3 -- both applied on the GLOBAL src addr, inverted on ds_read.
// NOTE: residual SQ_LDS_BANK_CONFLICT ~5.2M is a counter floor (4 counts per wave64
// b128 LDS op = benign 2-lanes-per-bank aliasing), verified by Vs-removal A/B (R5).
__global__ __launch_bounds__(512, 4) void attn_kernel(
    const ushort* __restrict__ qT, const ushort* __restrict__ kT,
    const ushort* __restrict__ vB, ushort* __restrict__ Op,
    float* __restrict__ Lv) {
  __shared__ __align__(16) ushort Ks[2][MT * 128];   // 2 x 8 KB (chunk-swizzled by row&7)
  __shared__ __align__(16) ushort Vs[2][C_ * MT];    // 2 x 8 KB (chunk-swizzled by (c>>1)&3)
  __shared__ __align__(16) ushort Ps[2][128 * PLD];  // 2 x 10 KB, double-buffered
  __shared__ float lpart[8][2][16];                  // 1 KB
  int sp = blockIdx.x & 3;
  int qblk = (blockIdx.x >> 2) & 31;
  int b = blockIdx.x >> 7;
  int n0 = qblk * 128;
  int tid = threadIdx.x, lane = tid & 63, w = tid >> 6;
  int col = lane & 15, quad = lane >> 4;
  int wu = __builtin_amdgcn_readfirstlane(w);
  int mtw = w & 1, qg = w >> 1;   // S-phase roles
  int qh = w & 1, cq = w >> 1;    // PV-phase roles
  const ushort* kTb = kT + (size_t)b * N_ * C_;
  const ushort* vBb = vB + (size_t)b * C_ * N_;

  bf16x8 qf[2][4];   // Q B-frags for this wave's 32 S-rows (q-group qg)
  #pragma unroll
  for (int qt = 0; qt < 2; ++qt)
    #pragma unroll
    for (int kc = 0; kc < 4; ++kc)
      qf[qt][kc] = *(const bf16x8*)(qT + ((size_t)b * N_ + n0 + qg * 32 + qt * 16 + col) * C_ + kc * 32 + quad * 8);

  floatx4 Oacc[4][2];   // [qt over q-half 64][ct over 32 c]
  #pragma unroll
  for (int qt = 0; qt < 4; ++qt)
    #pragma unroll
    for (int ct = 0; ct < 2; ++ct) Oacc[qt][ct] = (floatx4)0.f;
  float lacc[2] = {0.f, 0.f};   // per-lane l partials for S q-tiles (m-half mtw only)

  const int m00 = sp * 1024;

  // hoisted per-lane staging pointers: advance by constants each STAGE
  // K: row r = wu*4 + (lane>>4), 16B chunk pos = (lane&15) ^ (r&7)
  // V: chan c = wu*16 + (lane>>2), m-chunk mc = (lane&3) ^ ((lane>>3)&3)
  const ushort* kgp;
  const ushort* vgp;
  {
    int r = wu * 4 + (lane >> 4);
    int pos = (lane & 15) ^ (r & 7);
    kgp = kTb + (size_t)(m00 + r) * 128 + pos * 8;
    int c = wu * 16 + (lane >> 2);
    int mc = (lane & 3) ^ ((lane >> 3) & 3);
    vgp = vBb + (size_t)c * N_ + m00 + mc * 8;
  }

  #define STAGE(buf)                                   \
    {                                                  \
      gl2lds16(kgp, &Ks[buf][wu * 512]);               \
      gl2lds16(vgp, &Vs[buf][wu * 512]);               \
      kgp += MT * 128;                                 \
      vgp += MT;                                       \
    }

  // S^T for tile in KsB: rows m = mtw*16+quad*4+r, cols q = qg*32+qt*16+col
  #define S_COMPUTE(KsB, st)                                                          \
    {                                                                                 \
      int row = mtw * 16 + col;                                                       \
      bf16x8 kf[4];                                                                   \
      _Pragma("unroll")                                                               \
      for (int kc = 0; kc < 4; ++kc)                                                  \
        kf[kc] = *(const bf16x8*)&(KsB)[row * 128 + (((4 * kc + quad) ^ (col & 7)) * 8)]; \
      __builtin_amdgcn_s_setprio(1);                                                  \
      _Pragma("unroll")                                                               \
      for (int qt = 0; qt < 2; ++qt) {                                                \
        floatx4 acc = (floatx4)0.f;                                                   \
        _Pragma("unroll")                                                             \
        for (int kc = 0; kc < 4; ++kc)                                                \
          acc = __builtin_amdgcn_mfma_f32_16x16x32_bf16(kf[kc], qf[qt][kc], acc, 0, 0, 0); \
        st[qt] = acc;                                                                 \
      }                                                                               \
      __builtin_amdgcn_s_setprio(0);                                                  \
    }

  #define SOFTMAX_WRITE(PsB, st)                                                      \
    {                                                                                 \
      _Pragma("unroll")                                                               \
      for (int qt = 0; qt < 2; ++qt) {                                                \
        int prow = (qg * 32 + qt * 16 + col) * PLD + mtw * 16;                        \
        float p0 = fexp2(st[qt][0]);                                                  \
        float p1 = fexp2(st[qt][1]);                                                  \
        float p2 = fexp2(st[qt][2]);                                                  \
        float p3 = fexp2(st[qt][3]);                                                  \
        uint2 pk = { pkbf(p1, p0), pkbf(p3, p2) };                                    \
        *(uint2*)&(PsB)[prow + quad * 4] = pk;                                        \
        lacc[qt] += (p0 + p1) + (p2 + p3);                                            \
      }                                                                               \
    }

  // inverse V swizzle: chunk j = quad ^ ((c>>1)&3), and (c>>1)&3 == (col>>1)&3 here
  #define V_LOAD(VsB, vfp)                                                            \
    {                                                                                 \
      _Pragma("unroll")                                                               \
      for (int ct = 0; ct < 2; ++ct)                                                  \
        vfp[ct] = *(const bf16x8*)&(VsB)[(cq * 32 + ct * 16 + col) * MT +             \
                                         ((quad ^ ((col >> 1) & 3)) * 8)];            \
    }

  #define PV_COMPUTE(PsB, vfp)                                                        \
    {                                                                                 \
      __builtin_amdgcn_s_setprio(1);                                                  \
      _Pragma("unroll")                                                               \
      for (int qt = 0; qt < 4; ++qt) {                                                \
        bf16x8 pf = *(const bf16x8*)&(PsB)[(qh * 64 + qt * 16 + col) * PLD + quad * 8]; \
        _Pragma("unroll")                                                             \
        for (int ct = 0; ct < 2; ++ct)                                                \
          Oacc[qt][ct] = __builtin_amdgcn_mfma_f32_16x16x32_bf16(pf, vfp[ct], Oacc[qt][ct], 0, 0, 0); \
      }                                                                               \
      __builtin_amdgcn_s_setprio(0);                                                  \
    }

  floatx4 st[2];
  bf16x8 vfp[2];

  STAGE(0);
  __syncthreads();

  // ---- t = 0 (no PV yet) ----
  STAGE(1);
  S_COMPUTE(Ks[0], st);
  SOFTMAX_WRITE(Ps[0], st);
  V_LOAD(Vs[0], vfp);
  __syncthreads();

  // ---- steady state t = 1..30: S(t) ; PV(t-1) ; softmax(t) ; vload(t) ; barrier ----
  for (int t = 1; t < 31; ++t) {
    STAGE((t + 1) & 1);
    S_COMPUTE(Ks[t & 1], st);
    PV_COMPUTE(Ps[(t - 1) & 1], vfp);
    SOFTMAX_WRITE(Ps[t & 1], st);
    V_LOAD(Vs[t & 1], vfp);
    __syncthreads();
  }

  // ---- t = 31 (no stage) ----
  S_COMPUTE(Ks[1], st);
  PV_COMPUTE(Ps[0], vfp);
  SOFTMAX_WRITE(Ps[1], st);
  V_LOAD(Vs[1], vfp);
  __syncthreads();

  // ---- drain PV(31) ----
  PV_COMPUTE(Ps[1], vfp);

  // epilogue: Op[sp][b][n][c] bf16 (unnormalized)
  ushort* OpB = Op + (((size_t)sp * B_ + b) * N_ + n0) * C_;
  #pragma unroll
  for (int qt = 0; qt < 4; ++qt)
    #pragma unroll
    for (int ct = 0; ct < 2; ++ct)
      #pragma unroll
      for (int r = 0; r < 4; ++r)
        OpB[(size_t)(qh * 64 + qt * 16 + quad * 4 + r) * C_ + cq * 32 + ct * 16 + col] =
            f2bf(Oacc[qt][ct][r]);
  // l: reduce within wave (over quads), then combine the two m-halves via LDS
  #pragma unroll
  for (int qt = 0; qt < 2; ++qt) {
    float lsum = lacc[qt];
    lsum += __shfl_xor(lsum, 16, 64);
    lsum += __shfl_xor(lsum, 32, 64);
    if (quad == 0) lpart[w][qt][col] = lsum;
  }
  __syncthreads();
  if ((w & 1) == 0 && quad == 0) {
    #pragma unroll
    for (int qt = 0; qt < 2; ++qt) {
      int idx = b * N_ + n0 + (w >> 1) * 32 + qt * 16 + col;
      Lv[(size_t)sp * (B_ * N_) + idx] = lpart[w][qt][col] + lpart[w + 1][qt][col];
    }
  }
}

// ---------------- fused merge(4 splits, no-max) + proj MFMA + residual ----------------
// grid 512 = (b, 32-n tile); weight frags reused across n-halves; out/x rows 128B.
__global__ __launch_bounds__(256) void mergeproj_kernel(
    const ushort* __restrict__ Op, const float* __restrict__ Lv,
    const ushort* __restrict__ wpB, const float* __restrict__ bp,
    const float* __restrict__ x, float* __restrict__ out) {
  __shared__ __align__(16) ushort tile[32 * HLD];
  int tid = threadIdx.x;
  int b = blockIdx.x >> 7;
  int n0 = (blockIdx.x & 127) * 32;
  #pragma unroll
  for (int rep = 0; rep < 2; ++rep) {
    int idx = tid + rep * 256;
    int n = idx >> 4, cc = idx & 15;
    int nIdx = b * N_ + n0 + n;
    float den = Lv[0 * (B_ * N_) + nIdx] + Lv[1 * (B_ * N_) + nIdx] +
                Lv[2 * (B_ * N_) + nIdx] + Lv[3 * (B_ * N_) + nIdx];
    float inv = 1.f / den;
    float o[8];
    #pragma unroll
    for (int j = 0; j < 8; ++j) o[j] = 0.f;
    #pragma unroll
    for (int sp = 0; sp < NSPLIT; ++sp) {
      uint4 d = *(const uint4*)&Op[((size_t)sp * (B_ * N_) + nIdx) * C_ + cc * 8];
      unsigned dd[4] = {d.x, d.y, d.z, d.w};
      #pragma unroll
      for (int j = 0; j < 4; ++j) {
        o[j * 2]     += bf2f((ushort)(dd[j] & 0xFFFF));
        o[j * 2 + 1] += bf2f((ushort)(dd[j] >> 16));
      }
    }
    uint4 res;
    res.x = pkbf(o[1] * inv, o[0] * inv);
    res.y = pkbf(o[3] * inv, o[2] * inv);
    res.z = pkbf(o[5] * inv, o[4] * inv);
    res.w = pkbf(o[7] * inv, o[6] * inv);
    *(uint4*)&tile[n * HLD + cc * 8] = res;
  }
  __syncthreads();
  int lane = tid & 63, w = tid >> 6;
  int col = lane & 15, quad = lane >> 4;
  int oh = w * 32;
  bf16x8 hf[2][4];
  #pragma unroll
  for (int nh = 0; nh < 2; ++nh)
    #pragma unroll
    for (int kc = 0; kc < 4; ++kc)
      hf[nh][kc] = *(const bf16x8*)&tile[(nh * 16 + col) * HLD + kc * 32 + quad * 8];
  #pragma unroll
  for (int ot = 0; ot < 2; ++ot) {
    int o0 = oh + ot * 16;
    floatx4 acc[2] = {(floatx4)0.f, (floatx4)0.f};
    #pragma unroll
    for (int kc = 0; kc < 4; ++kc) {
      int wo = (o0 + col) * C_ + kc * 32 + quad * 8;
      bf16x8 wf = *(const bf16x8*)&wpB[wo];
      #pragma unroll
      for (int nh = 0; nh < 2; ++nh)
        acc[nh] = __builtin_amdgcn_mfma_f32_16x16x32_bf16(wf, hf[nh][kc], acc[nh], 0, 0, 0);
    }
    float4 bpv = *(const float4*)&bp[o0 + quad * 4];
    float bb[4] = {bpv.x, bpv.y, bpv.z, bpv.w};
    #pragma unroll
    for (int nh = 0; nh < 2; ++nh)
      #pragma unroll
      for (int r = 0; r < 4; ++r) {
        size_t idx = ((size_t)b * C_ + o0 + quad * 4 + r) * N_ + n0 + nh * 16 + col;
        out[idx] = acc[nh][r] + bb[r] + x[idx];
      }
  }
}

extern "C" void kernel_launch(void* const* d_in, const int* in_sizes, int n_in,
                              void* d_out, int out_size, void* d_ws, size_t ws_size,
                              hipStream_t stream) {
  const float* x        = (const float*)d_in[0];
  const float* gn_scale = (const float*)d_in[1];
  const float* gn_bias  = (const float*)d_in[2];
  const float* wq = (const float*)d_in[3];
  const float* bq = (const float*)d_in[4];
  const float* wk = (const float*)d_in[5];
  const float* bk = (const float*)d_in[6];
  const float* wv = (const float*)d_in[7];
  const float* bv = (const float*)d_in[8];
  const float* wp = (const float*)d_in[9];
  const float* bp = (const float*)d_in[10];
  float* out = (float*)d_out;

  char* ws = (char*)d_ws;
  float*  Lv    = (float*)(ws + 262144);
  ushort* wB    = (ushort*)(ws + 524288);
  float*  gstat = (float*)(ws + 655360);
  ushort* qT    = (ushort*)(ws + (4u << 20));
  ushort* kT    = (ushort*)(ws + (8u << 20));
  ushort* vB    = (ushort*)(ws + (12u << 20));
  ushort* Op    = (ushort*)(ws + (16u << 20));
  ushort* wpB   = wB + 49152;

  prep_kernel<<<512, 256, 0, stream>>>(x, gstat, wq, wk, wv, wp, wB);
  gnqkv_kernel<<<512, 256, 0, stream>>>(x, gstat, gn_scale, gn_bias, wB, bq, bk, bv, qT, kT, vB);
  attn_kernel<<<512, 512, 0, stream>>>(qT, kT, vB, Op, Lv);
  mergeproj_kernel<<<512, 256, 0, stream>>>(Op, Lv, wpB, bp, x, out);
}

// Round 12
// 140.750 us; speedup vs baseline: 2.2311x; 1.0141x over previous
//
#include <hip/hip_runtime.h>
#include <math.h>

#define B_ 4
#define C_ 128
#define N_ 4096
#define NSPLIT 4
#define MT 32     // keys per iteration
#define PLD 40    // Ps row stride (shorts): 32 + 8 pad (80 B, 16B-divisible)
#define HLD 136   // h/q/k tile row stride (shorts): 128 + 8 pad
#define VTLD 40   // gnqkv v-tile row stride (shorts): 32 + 8 pad (80 B, 16B-divisible)

typedef float floatx4 __attribute__((ext_vector_type(4)));
typedef short bf16x8 __attribute__((ext_vector_type(8)));

__device__ __forceinline__ ushort f2bf(float f) {  // RNE
  unsigned u = __float_as_uint(f);
  return (ushort)((u + 0x7FFF + ((u >> 16) & 1)) >> 16);
}
__device__ __forceinline__ float bf2f(ushort u) {
  return __uint_as_float(((unsigned)u) << 16);
}
// pack two floats -> (hi16(a)<<16)|hi16(b), round-half-up
__device__ __forceinline__ unsigned pkbf(float a, float b) {
  return __builtin_amdgcn_perm(__float_as_uint(a) + 0x8000u,
                               __float_as_uint(b) + 0x8000u, 0x07060302u);
}
// raw v_exp_f32 (exp2) -- OCML exp2f is ~10 inst of denorm/range handling we don't need
__device__ __forceinline__ float fexp2(float x) {
#if __has_builtin(__builtin_amdgcn_exp2f)
  return __builtin_amdgcn_exp2f(x);
#else
  return exp2f(x);
#endif
}
// async global -> LDS, 16B per lane; LDS dest = uniform base + lane*16
__device__ __forceinline__ void gl2lds16(const ushort* g, ushort* l) {
  __builtin_amdgcn_global_load_lds(
      (const __attribute__((address_space(1))) void*)g,
      (__attribute__((address_space(3))) void*)l, 16, 0, 0);
}

// NOTE (R7-R10): single-kernel fusion with grid-wide barriers was tried 4 ways --
// cooperative launch (failed under graph capture), flat atomic counter (77us/bar),
// hierarchical counters (46us/bar), flag+central-gen (60us/bar).  Software grid
// barriers cost >=45us each on MI355X.  BUT the fused runs calibrated the phase
// execution: P0+P1+P3 took only ~25us with 512-thread blocks vs ~95us as standalone
// 256-thread kernels -> those kernels were occupancy-starved (8 waves/CU), not
// overhead-bound.  R11 fix: standalone kernels now use the fused 512-thread bodies.

// ---------------- fused: gn_stats (blocks 0..255) + weight cvt (256..511) ----------------
__global__ __launch_bounds__(512) void prep_kernel(
    const float* __restrict__ x, float* __restrict__ gstat,
    const float* __restrict__ wq, const float* __restrict__ wk,
    const float* __restrict__ wv, const float* __restrict__ wp,
    ushort* __restrict__ wB) {
  int tid = threadIdx.x;
  if (blockIdx.x >= 256) {   // weight convert: 65536 elems over 256 blocks
    if (tid < 256) {
      int i = (blockIdx.x - 256) * 256 + tid;
      int m = i >> 14, j = i & 16383;
      const float* src = (m == 0) ? wq : (m == 1) ? wk : (m == 2) ? wv : wp;
      wB[i] = f2bf(src[j]);
    }
    return;
  }
  int b = blockIdx.x >> 6, g = (blockIdx.x >> 3) & 7, part = blockIdx.x & 7;
  const float4* xp = (const float4*)(x + (size_t)(b * C_ + g * 16) * N_) + part * 2048;
  float s = 0.f, ss = 0.f;
  for (int i = tid; i < 2048; i += 512) {
    float4 v = xp[i];
    s += v.x + v.y + v.z + v.w;
    ss += v.x * v.x + v.y * v.y + v.z * v.z + v.w * v.w;
  }
  #pragma unroll
  for (int o = 32; o > 0; o >>= 1) {
    s += __shfl_down(s, o, 64);
    ss += __shfl_down(ss, o, 64);
  }
  __shared__ float rs[8], rss[8];
  int wid = tid >> 6, lane = tid & 63;
  if (lane == 0) { rs[wid] = s; rss[wid] = ss; }
  __syncthreads();
  if (tid == 0) {
    float S = 0.f, SS = 0.f;
    #pragma unroll
    for (int k = 0; k < 8; ++k) { S += rs[k]; SS += rss[k]; }
    int slot = (b * 8 + g) * 8 + part;
    gstat[slot]       = S;
    gstat[256 + slot] = SS;
  }
}

// ---------------- fused GN-apply + QKV MFMA: grid 512 = (b, 32-n tile) ----------------
// 512 threads = 8 waves x 16 out-ch (body lifted verbatim from the verified fused P1);
// 16 waves/CU (was 8 with 256-thread blocks -> latency-bound).  Weight A-frags loaded
// once per kc, reused for both n-halves.
__global__ __launch_bounds__(512, 4) void gnqkv_kernel(
    const float* __restrict__ x, const float* __restrict__ gstat,
    const float* __restrict__ scale, const float* __restrict__ bias,
    const ushort* __restrict__ wB,
    const float* __restrict__ bq, const float* __restrict__ bk,
    const float* __restrict__ bv,
    ushort* __restrict__ qT, ushort* __restrict__ kT, ushort* __restrict__ vB) {
  __shared__ __align__(16) ushort hs[32][HLD];
  __shared__ __align__(16) ushort Qt[32][HLD];
  __shared__ __align__(16) ushort Kt[32][HLD];
  __shared__ __align__(16) ushort Vt[128][VTLD];
  __shared__ float sSc[C_], sBi[C_];
  int tid = threadIdx.x;
  int b = blockIdx.x >> 7;
  int n0 = (blockIdx.x & 127) * 32;
  if (tid < 128) {
    int g = tid >> 4;
    float S = 0.f, SS = 0.f;
    #pragma unroll
    for (int p = 0; p < 8; ++p) {
      S  += gstat[(b * 8 + g) * 8 + p];
      SS += gstat[256 + (b * 8 + g) * 8 + p];
    }
    float mu = S * (1.f / 65536.f);
    float var = SS * (1.f / 65536.f) - mu * mu;
    float rstd = rsqrtf(var + 1e-6f);
    float sc = scale[tid] * rstd;
    sSc[tid] = sc;
    sBi[tid] = bias[tid] - mu * sc;
  }
  __syncthreads();
  #pragma unroll
  for (int k2 = 0; k2 < 2; ++k2) {   // 128 c x 8 float4 (32 n) = 1024 items
    int i = tid + k2 * 512;
    int c = i >> 3, n4 = i & 7;
    float4 v = *(const float4*)(x + (size_t)(b * C_ + c) * N_ + n0 + n4 * 4);
    float sc = sSc[c], bi = sBi[c];
    hs[n4 * 4 + 0][c] = f2bf(v.x * sc + bi);
    hs[n4 * 4 + 1][c] = f2bf(v.y * sc + bi);
    hs[n4 * 4 + 2][c] = f2bf(v.z * sc + bi);
    hs[n4 * 4 + 3][c] = f2bf(v.w * sc + bi);
  }
  __syncthreads();
  int lane = tid & 63, w = tid >> 6;
  int col = lane & 15, quad = lane >> 4;
  int o0 = w * 16;   // 8 waves x 16 output channels
  bf16x8 hf[2][4];   // [n-half][kc]
  #pragma unroll
  for (int nh = 0; nh < 2; ++nh)
    #pragma unroll
    for (int kc = 0; kc < 4; ++kc)
      hf[nh][kc] = *(const bf16x8*)&hs[nh * 16 + col][kc * 32 + quad * 8];
  const ushort* Wq = wB;
  const ushort* Wk = wB + 16384;
  const ushort* Wv = wB + 32768;
  const float scl = 0.12751879752224991f;  // 128^-0.5 * log2(e)
  floatx4 aq[2] = {(floatx4)0.f, (floatx4)0.f};
  floatx4 ak[2] = {(floatx4)0.f, (floatx4)0.f};
  floatx4 av[2] = {(floatx4)0.f, (floatx4)0.f};
  #pragma unroll
  for (int kc = 0; kc < 4; ++kc) {
    int wo = (o0 + col) * C_ + kc * 32 + quad * 8;
    bf16x8 wqf = *(const bf16x8*)&Wq[wo];
    bf16x8 wkf = *(const bf16x8*)&Wk[wo];
    bf16x8 wvf = *(const bf16x8*)&Wv[wo];
    #pragma unroll
    for (int nh = 0; nh < 2; ++nh) {
      aq[nh] = __builtin_amdgcn_mfma_f32_16x16x32_bf16(wqf, hf[nh][kc], aq[nh], 0, 0, 0);
      ak[nh] = __builtin_amdgcn_mfma_f32_16x16x32_bf16(wkf, hf[nh][kc], ak[nh], 0, 0, 0);
      av[nh] = __builtin_amdgcn_mfma_f32_16x16x32_bf16(wvf, hf[nh][kc], av[nh], 0, 0, 0);
    }
  }
  float4 bqv = *(const float4*)&bq[o0 + quad * 4];
  float4 bkv = *(const float4*)&bk[o0 + quad * 4];
  float4 bvv = *(const float4*)&bv[o0 + quad * 4];
  #pragma unroll
  for (int nh = 0; nh < 2; ++nh) {
    uint2 qs = { pkbf((aq[nh][1] + bqv.y) * scl, (aq[nh][0] + bqv.x) * scl),
                 pkbf((aq[nh][3] + bqv.w) * scl, (aq[nh][2] + bqv.z) * scl) };
    uint2 ks = { pkbf(ak[nh][1] + bkv.y, ak[nh][0] + bkv.x),
                 pkbf(ak[nh][3] + bkv.w, ak[nh][2] + bkv.z) };
    *(uint2*)&Qt[nh * 16 + col][o0 + quad * 4] = qs;
    *(uint2*)&Kt[nh * 16 + col][o0 + quad * 4] = ks;
    float vv[4] = {av[nh][0] + bvv.x, av[nh][1] + bvv.y,
                   av[nh][2] + bvv.z, av[nh][3] + bvv.w};
    #pragma unroll
    for (int r = 0; r < 4; ++r)
      Vt[o0 + quad * 4 + r][nh * 16 + col] = f2bf(vv[r]);
  }
  __syncthreads();
  {
    int row = tid >> 4, seg = tid & 15;   // 32 rows x 16 segs
    size_t dst = ((size_t)b * N_ + n0 + row) * C_ + seg * 8;
    *(uint4*)(qT + dst) = *(const uint4*)&Qt[row][seg * 8];
    *(uint4*)(kT + dst) = *(const uint4*)&Kt[row][seg * 8];
  }
  {
    int o = tid >> 2, seg = tid & 3;      // 128 ch x 4 segs
    *(uint4*)(vB + ((size_t)b * C_ + o) * N_ + n0 + seg * 8) = *(const uint4*)&Vt[o][seg * 8];
  }
}

// ---------------- MFMA flash attention: 8-wave blocks, split-m S + split-qc PV ----------
// grid 512: sp=bx&3 (fastest; XCD x sees only sp=x&3 -> K/V slice L2-resident),
// qblk=(bx>>2)&31, b=bx>>7.  512 thr = 8 waves.
// S-phase:  wave w -> m-half mtw=w&1 (16 keys), q-group qg=w>>1 (32 q).
// PV-phase: wave w -> q-half qh=w&1 (64 q), channel-quarter cq=w>>1 (32 c).
// SOFTWARE PIPELINE (1 barrier/iter): Ps double-buffered; PV runs one tile behind.
// exp2 = raw v_exp_f32. STAGE pointers hoisted. K chunk-swizzled by row&7; Vs m-chunk
// swizzled by (c>>1)&3 -- both applied on the GLOBAL src addr, inverted on ds_read.
// NOTE: residual SQ_LDS_BANK_CONFLICT ~5.2M is a counter floor (4 counts per wave64
// b128 LDS op = benign 2-lanes-per-bank aliasing), verified by Vs-removal A/B (R5).
__global__ __launch_bounds__(512, 4) void attn_kernel(
    const ushort* __restrict__ qT, const ushort* __restrict__ kT,
    const ushort* __restrict__ vB, ushort* __restrict__ Op,
    float* __restrict__ Lv) {
  __shared__ __align__(16) ushort Ks[2][MT * 128];   // 2 x 8 KB (chunk-swizzled by row&7)
  __shared__ __align__(16) ushort Vs[2][C_ * MT];    // 2 x 8 KB (chunk-swizzled by (c>>1)&3)
  __shared__ __align__(16) ushort Ps[2][128 * PLD];  // 2 x 10 KB, double-buffered
  __shared__ float lpart[8][2][16];                  // 1 KB
  int sp = blockIdx.x & 3;
  int qblk = (blockIdx.x >> 2) & 31;
  int b = blockIdx.x >> 7;
  int n0 = qblk * 128;
  int tid = threadIdx.x, lane = tid & 63, w = tid >> 6;
  int col = lane & 15, quad = lane >> 4;
  int wu = __builtin_amdgcn_readfirstlane(w);
  int mtw = w & 1, qg = w >> 1;   // S-phase roles
  int qh = w & 1, cq = w >> 1;    // PV-phase roles
  const ushort* kTb = kT + (size_t)b * N_ * C_;
  const ushort* vBb = vB + (size_t)b * C_ * N_;

  bf16x8 qf[2][4];   // Q B-frags for this wave's 32 S-rows (q-group qg)
  #pragma unroll
  for (int qt = 0; qt < 2; ++qt)
    #pragma unroll
    for (int kc = 0; kc < 4; ++kc)
      qf[qt][kc] = *(const bf16x8*)(qT + ((size_t)b * N_ + n0 + qg * 32 + qt * 16 + col) * C_ + kc * 32 + quad * 8);

  floatx4 Oacc[4][2];   // [qt over q-half 64][ct over 32 c]
  #pragma unroll
  for (int qt = 0; qt < 4; ++qt)
    #pragma unroll
    for (int ct = 0; ct < 2; ++ct) Oacc[qt][ct] = (floatx4)0.f;
  float lacc[2] = {0.f, 0.f};   // per-lane l partials for S q-tiles (m-half mtw only)

  const int m00 = sp * 1024;

  // hoisted per-lane staging pointers: advance by constants each STAGE
  // K: row r = wu*4 + (lane>>4), 16B chunk pos = (lane&15) ^ (r&7)
  // V: chan c = wu*16 + (lane>>2), m-chunk mc = (lane&3) ^ ((lane>>3)&3)
  const ushort* kgp;
  const ushort* vgp;
  {
    int r = wu * 4 + (lane >> 4);
    int pos = (lane & 15) ^ (r & 7);
    kgp = kTb + (size_t)(m00 + r) * 128 + pos * 8;
    int c = wu * 16 + (lane >> 2);
    int mc = (lane & 3) ^ ((lane >> 3) & 3);
    vgp = vBb + (size_t)c * N_ + m00 + mc * 8;
  }

  #define STAGE(buf)                                   \
    {                                                  \
      gl2lds16(kgp, &Ks[buf][wu * 512]);               \
      gl2lds16(vgp, &Vs[buf][wu * 512]);               \
      kgp += MT * 128;                                 \
      vgp += MT;                                       \
    }

  // S^T for tile in KsB: rows m = mtw*16+quad*4+r, cols q = qg*32+qt*16+col
  #define S_COMPUTE(KsB, st)                                                          \
    {                                                                                 \
      int row = mtw * 16 + col;                                                       \
      bf16x8 kf[4];                                                                   \
      _Pragma("unroll")                                                               \
      for (int kc = 0; kc < 4; ++kc)                                                  \
        kf[kc] = *(const bf16x8*)&(KsB)[row * 128 + (((4 * kc + quad) ^ (col & 7)) * 8)]; \
      __builtin_amdgcn_s_setprio(1);                                                  \
      _Pragma("unroll")                                                               \
      for (int qt = 0; qt < 2; ++qt) {                                                \
        floatx4 acc = (floatx4)0.f;                                                   \
        _Pragma("unroll")                                                             \
        for (int kc = 0; kc < 4; ++kc)                                                \
          acc = __builtin_amdgcn_mfma_f32_16x16x32_bf16(kf[kc], qf[qt][kc], acc, 0, 0, 0); \
        st[qt] = acc;                                                                 \
      }                                                                               \
      __builtin_amdgcn_s_setprio(0);                                                  \
    }

  #define SOFTMAX_WRITE(PsB, st)                                                      \
    {                                                                                 \
      _Pragma("unroll")                                                               \
      for (int qt = 0; qt < 2; ++qt) {                                                \
        int prow = (qg * 32 + qt * 16 + col) * PLD + mtw * 16;                        \
        float p0 = fexp2(st[qt][0]);                                                  \
        float p1 = fexp2(st[qt][1]);                                                  \
        float p2 = fexp2(st[qt][2]);                                                  \
        float p3 = fexp2(st[qt][3]);                                                  \
        uint2 pk = { pkbf(p1, p0), pkbf(p3, p2) };                                    \
        *(uint2*)&(PsB)[prow + quad * 4] = pk;                                        \
        lacc[qt] += (p0 + p1) + (p2 + p3);                                            \
      }                                                                               \
    }

  // inverse V swizzle: chunk j = quad ^ ((c>>1)&3), and (c>>1)&3 == (col>>1)&3 here
  #define V_LOAD(VsB, vfp)                                                            \
    {                                                                                 \
      _Pragma("unroll")                                                               \
      for (int ct = 0; ct < 2; ++ct)                                                  \
        vfp[ct] = *(const bf16x8*)&(VsB)[(cq * 32 + ct * 16 + col) * MT +             \
                                         ((quad ^ ((col >> 1) & 3)) * 8)];            \
    }

  #define PV_COMPUTE(PsB, vfp)                                                        \
    {                                                                                 \
      __builtin_amdgcn_s_setprio(1);                                                  \
      _Pragma("unroll")                                                               \
      for (int qt = 0; qt < 4; ++qt) {                                                \
        bf16x8 pf = *(const bf16x8*)&(PsB)[(qh * 64 + qt * 16 + col) * PLD + quad * 8]; \
        _Pragma("unroll")                                                             \
        for (int ct = 0; ct < 2; ++ct)                                                \
          Oacc[qt][ct] = __builtin_amdgcn_mfma_f32_16x16x32_bf16(pf, vfp[ct], Oacc[qt][ct], 0, 0, 0); \
      }                                                                               \
      __builtin_amdgcn_s_setprio(0);                                                  \
    }

  floatx4 st[2];
  bf16x8 vfp[2];

  STAGE(0);
  __syncthreads();

  // ---- t = 0 (no PV yet) ----
  STAGE(1);
  S_COMPUTE(Ks[0], st);
  SOFTMAX_WRITE(Ps[0], st);
  V_LOAD(Vs[0], vfp);
  __syncthreads();

  // ---- steady state t = 1..30: S(t) ; PV(t-1) ; softmax(t) ; vload(t) ; barrier ----
  for (int t = 1; t < 31; ++t) {
    STAGE((t + 1) & 1);
    S_COMPUTE(Ks[t & 1], st);
    PV_COMPUTE(Ps[(t - 1) & 1], vfp);
    SOFTMAX_WRITE(Ps[t & 1], st);
    V_LOAD(Vs[t & 1], vfp);
    __syncthreads();
  }

  // ---- t = 31 (no stage) ----
  S_COMPUTE(Ks[1], st);
  PV_COMPUTE(Ps[0], vfp);
  SOFTMAX_WRITE(Ps[1], st);
  V_LOAD(Vs[1], vfp);
  __syncthreads();

  // ---- drain PV(31) ----
  PV_COMPUTE(Ps[1], vfp);

  // epilogue: Op[sp][b][n][c] bf16 (unnormalized)
  ushort* OpB = Op + (((size_t)sp * B_ + b) * N_ + n0) * C_;
  #pragma unroll
  for (int qt = 0; qt < 4; ++qt)
    #pragma unroll
    for (int ct = 0; ct < 2; ++ct)
      #pragma unroll
      for (int r = 0; r < 4; ++r)
        OpB[(size_t)(qh * 64 + qt * 16 + quad * 4 + r) * C_ + cq * 32 + ct * 16 + col] =
            f2bf(Oacc[qt][ct][r]);
  // l: reduce within wave (over quads), then combine the two m-halves via LDS
  #pragma unroll
  for (int qt = 0; qt < 2; ++qt) {
    float lsum = lacc[qt];
    lsum += __shfl_xor(lsum, 16, 64);
    lsum += __shfl_xor(lsum, 32, 64);
    if (quad == 0) lpart[w][qt][col] = lsum;
  }
  __syncthreads();
  if ((w & 1) == 0 && quad == 0) {
    #pragma unroll
    for (int qt = 0; qt < 2; ++qt) {
      int idx = b * N_ + n0 + (w >> 1) * 32 + qt * 16 + col;
      Lv[(size_t)sp * (B_ * N_) + idx] = lpart[w][qt][col] + lpart[w + 1][qt][col];
    }
  }
}

// ---------------- fused merge(4 splits, no-max) + proj MFMA + residual ----------------
// grid 512 = (b, 32-n tile), 512 threads (verified fused-P3 body).  Merge covers all
// 32n x 16cc in one pass; 8 waves x 16 out-ch; weight frags reused across n-halves.
__global__ __launch_bounds__(512, 4) void mergeproj_kernel(
    const ushort* __restrict__ Op, const float* __restrict__ Lv,
    const ushort* __restrict__ wpB, const float* __restrict__ bp,
    const float* __restrict__ x, float* __restrict__ out) {
  __shared__ __align__(16) ushort tile[32 * HLD];
  int tid = threadIdx.x;
  int b = blockIdx.x >> 7;
  int n0 = (blockIdx.x & 127) * 32;
  {
    int n = tid >> 4, cc = tid & 15;   // 32 n x 16 cc with 512 threads
    int nIdx = b * N_ + n0 + n;
    float den = Lv[0 * (B_ * N_) + nIdx] + Lv[1 * (B_ * N_) + nIdx] +
                Lv[2 * (B_ * N_) + nIdx] + Lv[3 * (B_ * N_) + nIdx];
    float inv = 1.f / den;
    float o[8];
    #pragma unroll
    for (int j = 0; j < 8; ++j) o[j] = 0.f;
    #pragma unroll
    for (int sp = 0; sp < NSPLIT; ++sp) {
      uint4 d = *(const uint4*)&Op[((size_t)sp * (B_ * N_) + nIdx) * C_ + cc * 8];
      unsigned dd[4] = {d.x, d.y, d.z, d.w};
      #pragma unroll
      for (int j = 0; j < 4; ++j) {
        o[j * 2]     += bf2f((ushort)(dd[j] & 0xFFFF));
        o[j * 2 + 1] += bf2f((ushort)(dd[j] >> 16));
      }
    }
    uint4 res;
    res.x = pkbf(o[1] * inv, o[0] * inv);
    res.y = pkbf(o[3] * inv, o[2] * inv);
    res.z = pkbf(o[5] * inv, o[4] * inv);
    res.w = pkbf(o[7] * inv, o[6] * inv);
    *(uint4*)&tile[n * HLD + cc * 8] = res;
  }
  __syncthreads();
  int lane = tid & 63, w = tid >> 6;
  int col = lane & 15, quad = lane >> 4;
  int o0 = w * 16;   // 8 waves x 16 output channels
  bf16x8 hf[2][4];
  #pragma unroll
  for (int nh = 0; nh < 2; ++nh)
    #pragma unroll
    for (int kc = 0; kc < 4; ++kc)
      hf[nh][kc] = *(const bf16x8*)&tile[(nh * 16 + col) * HLD + kc * 32 + quad * 8];
  floatx4 acc[2] = {(floatx4)0.f, (floatx4)0.f};
  #pragma unroll
  for (int kc = 0; kc < 4; ++kc) {
    int wo = (o0 + col) * C_ + kc * 32 + quad * 8;
    bf16x8 wf = *(const bf16x8*)&wpB[wo];
    #pragma unroll
    for (int nh = 0; nh < 2; ++nh)
      acc[nh] = __builtin_amdgcn_mfma_f32_16x16x32_bf16(wf, hf[nh][kc], acc[nh], 0, 0, 0);
  }
  float4 bpv = *(const float4*)&bp[o0 + quad * 4];
  float bb[4] = {bpv.x, bpv.y, bpv.z, bpv.w};
  #pragma unroll
  for (int nh = 0; nh < 2; ++nh)
    #pragma unroll
    for (int r = 0; r < 4; ++r) {
      size_t idx = ((size_t)b * C_ + o0 + quad * 4 + r) * N_ + n0 + nh * 16 + col;
      out[idx] = acc[nh][r] + bb[r] + x[idx];
    }
}

extern "C" void kernel_launch(void* const* d_in, const int* in_sizes, int n_in,
                              void* d_out, int out_size, void* d_ws, size_t ws_size,
                              hipStream_t stream) {
  const float* x        = (const float*)d_in[0];
  const float* gn_scale = (const float*)d_in[1];
  const float* gn_bias  = (const float*)d_in[2];
  const float* wq = (const float*)d_in[3];
  const float* bq = (const float*)d_in[4];
  const float* wk = (const float*)d_in[5];
  const float* bk = (const float*)d_in[6];
  const float* wv = (const float*)d_in[7];
  const float* bv = (const float*)d_in[8];
  const float* wp = (const float*)d_in[9];
  const float* bp = (const float*)d_in[10];
  float* out = (float*)d_out;

  char* ws = (char*)d_ws;
  float*  Lv    = (float*)(ws + 262144);
  ushort* wB    = (ushort*)(ws + 524288);
  float*  gstat = (float*)(ws + 655360);
  ushort* qT    = (ushort*)(ws + (4u << 20));
  ushort* kT    = (ushort*)(ws + (8u << 20));
  ushort* vB    = (ushort*)(ws + (12u << 20));
  ushort* Op    = (ushort*)(ws + (16u << 20));
  ushort* wpB   = wB + 49152;

  prep_kernel<<<512, 512, 0, stream>>>(x, gstat, wq, wk, wv, wp, wB);
  gnqkv_kernel<<<512, 512, 0, stream>>>(x, gstat, gn_scale, gn_bias, wB, bq, bk, bv, qT, kT, vB);
  attn_kernel<<<512, 512, 0, stream>>>(qT, kT, vB, Op, Lv);
  mergeproj_kernel<<<512, 512, 0, stream>>>(Op, Lv, wpB, bp, x, out);
}